// Round 1
// baseline (2824.431 us; speedup 1.0000x reference)
//
#include <hip/hip_runtime.h>
#include <math.h>

// Problem constants (B=2, L=2048, H=2048, K=H/NH=128)
#define B_ 2
#define L_ 2048
#define H_ 2048
#define KD_ 128
#define SCALE_ 0.08838834764831845f  // 128^-0.5
#define EPS_ 1e-5f

static __device__ __forceinline__ float sigmoidf_(float z) {
    return 1.0f / (1.0f + __expf(-z));
}

// ---------------------------------------------------------------------------
// Kernel 1: q_raw = x @ Wq^T, k_raw = x @ Wk^T  (M=4096, N=256, K=2048)
//   epilogue: q = silu(q_raw)*SCALE ; ks = sigmoid(k_raw) ; g = -log1p(exp(ks))
// 64x64 tile, 256 threads, 4x4 per thread.
// ---------------------------------------------------------------------------
__global__ __launch_bounds__(256) void qk_proj_kernel(
    const float* __restrict__ x, const float* __restrict__ Wq,
    const float* __restrict__ Wk, float* __restrict__ q,
    float* __restrict__ ks, float* __restrict__ g)
{
    __shared__ float As[16][65];
    __shared__ float Bs[16][65];
    const int tid = threadIdx.x;
    const int tx = tid & 15, ty = tid >> 4;
    const int m0 = blockIdx.x * 64;
    const int n0 = blockIdx.y * 64;
    float acc[4][4] = {};
    const int kk = tid & 15;
    const int rr = tid >> 4;
    for (int k0 = 0; k0 < H_; k0 += 16) {
        #pragma unroll
        for (int rit = 0; rit < 4; ++rit) {
            int r = rr + rit * 16;
            As[kk][r] = x[(size_t)(m0 + r) * H_ + k0 + kk];
            int n = n0 + r;
            const float* Wrow = (n < KD_) ? (Wq + (size_t)n * H_)
                                          : (Wk + (size_t)(n - KD_) * H_);
            Bs[kk][r] = Wrow[k0 + kk];
        }
        __syncthreads();
        #pragma unroll
        for (int k = 0; k < 16; ++k) {
            float a[4], b[4];
            #pragma unroll
            for (int i = 0; i < 4; ++i) a[i] = As[k][ty * 4 + i];
            #pragma unroll
            for (int j = 0; j < 4; ++j) b[j] = Bs[k][tx * 4 + j];
            #pragma unroll
            for (int i = 0; i < 4; ++i)
                #pragma unroll
                for (int j = 0; j < 4; ++j) acc[i][j] += a[i] * b[j];
        }
        __syncthreads();
    }
    #pragma unroll
    for (int i = 0; i < 4; ++i) {
        int m = m0 + ty * 4 + i;
        #pragma unroll
        for (int j = 0; j < 4; ++j) {
            int n = n0 + tx * 4 + j;
            float v = acc[i][j];
            if (n < KD_) {
                q[(size_t)m * KD_ + n] = v * sigmoidf_(v) * SCALE_;
            } else {
                float sk = sigmoidf_(v);
                ks[(size_t)m * KD_ + (n - KD_)] = sk;
                // g = log_sigmoid(-ks) = -softplus(ks); ks in (0,1) so exp is safe
                g[(size_t)m * KD_ + (n - KD_)] = -log1pf(__expf(sk));
            }
        }
    }
}

// ---------------------------------------------------------------------------
// Kernel 2: inclusive prefix sum of g along L per (batch, key-dim).
// One wave per (kd, b); each lane handles 32 consecutive timesteps.
// ---------------------------------------------------------------------------
__global__ __launch_bounds__(64) void gate_scan_kernel(
    const float* __restrict__ g, float* __restrict__ G)
{
    const int kd = blockIdx.x;   // 0..127
    const int b  = blockIdx.y;   // 0..1
    const int lane = threadIdx.x;
    const float* gp = g + (size_t)b * L_ * KD_ + kd;
    float* Gp = G + (size_t)b * L_ * KD_ + kd;
    float vals[32];
    float s = 0.f;
    const int t0 = lane * 32;
    #pragma unroll
    for (int j = 0; j < 32; ++j) { s += gp[(size_t)(t0 + j) * KD_]; vals[j] = s; }
    float incl = s;
    #pragma unroll
    for (int d = 1; d < 64; d <<= 1) {
        float n = __shfl_up(incl, d, 64);
        if (lane >= d) incl += n;
    }
    float excl = incl - s;
    #pragma unroll
    for (int j = 0; j < 32; ++j) Gp[(size_t)(t0 + j) * KD_] = excl + vals[j];
}

// ---------------------------------------------------------------------------
// Kernel 3: banded GLA attention.
// Decay <= 0.5/step => only previous chunk + current chunk matter (error <
// 0.5^65 ~ 2.7e-20, utterly below the 0.38 threshold).
// Block = (chunk c, batch b, v-tile of 128). Phase 1: P[64q x 128keys] =
// q~ . k~^T with q~ = q*exp(Gq - R), k~ = ks*exp(R - Gk), R = G[c*64-1].
// Worst-case |exponent| = 64*1.3133 = 84.05 < 88.7 => no fp32 overflow.
// Phase 2: o-tile[64 x 128] = P @ V (V = hidden_states rows).
// ---------------------------------------------------------------------------
__global__ __launch_bounds__(256) void gla_attn_kernel(
    const float* __restrict__ q, const float* __restrict__ ks,
    const float* __restrict__ G, const float* __restrict__ x,
    float* __restrict__ o)
{
    const int c  = blockIdx.x;  // 0..31
    const int b  = blockIdx.y;  // 0..1
    const int vt = blockIdx.z;  // 0..15
    const int tid = threadIdx.x;
    const int tx = tid & 15, ty = tid >> 4;

    // union region: phase1 qt(64x33)+kt(128x33) = 6336 floats; phase2 Vt(32x128)
    __shared__ float uni[6336];
    float (*qt)[33]  = (float(*)[33])uni;
    float (*kt)[33]  = (float(*)[33])(uni + 64 * 33);
    float (*Vt)[128] = (float(*)[128])uni;
    __shared__ float Psh[64][128];
    __shared__ float Rsh[128];

    const int q0 = c * 64;         // first query position in chunk
    const int kpos0 = q0 - 64;     // first key position (may be negative for c=0)
    const size_t rowbase = (size_t)b * L_;

    if (tid < 128)
        Rsh[tid] = (c > 0) ? G[(rowbase + q0 - 1) * KD_ + tid] : 0.f;
    __syncthreads();

    float acc[4][8] = {};
    const int skk = tid & 31;
    const int sr0 = tid >> 5;
    for (int k0 = 0; k0 < KD_; k0 += 32) {
        float Rv = Rsh[k0 + skk];
        #pragma unroll
        for (int r = sr0; r < 64; r += 8) {
            size_t idx = (rowbase + q0 + r) * (size_t)KD_ + k0 + skk;
            qt[r][skk] = q[idx] * __expf(G[idx] - Rv);
        }
        #pragma unroll
        for (int r = sr0; r < 128; r += 8) {
            int kp = kpos0 + r;
            float val = 0.f;
            if (kp >= 0) {
                size_t idx = (rowbase + kp) * (size_t)KD_ + k0 + skk;
                val = ks[idx] * __expf(Rv - G[idx]);
            }
            kt[r][skk] = val;  // zero for invalid keys => no inf/NaN in accum
        }
        __syncthreads();
        #pragma unroll
        for (int k = 0; k < 32; ++k) {
            float a[4], bb[8];
            #pragma unroll
            for (int i = 0; i < 4; ++i) a[i] = qt[ty * 4 + i][k];
            #pragma unroll
            for (int j = 0; j < 8; ++j) bb[j] = kt[tx * 8 + j][k];
            #pragma unroll
            for (int i = 0; i < 4; ++i)
                #pragma unroll
                for (int j = 0; j < 8; ++j) acc[i][j] += a[i] * bb[j];
        }
        __syncthreads();
    }
    // write P with causal mask (keypos <= querypos); non-causal accum may be
    // huge/inf but is overwritten (select, not multiply) so it never escapes.
    #pragma unroll
    for (int i = 0; i < 4; ++i) {
        int ti = ty * 4 + i;
        #pragma unroll
        for (int j = 0; j < 8; ++j) {
            int si = tx * 8 + j;
            int kp = kpos0 + si;
            Psh[ti][si] = (kp >= 0 && si <= ti + 64) ? acc[i][j] : 0.f;
        }
    }
    __syncthreads();

    // Phase 2: o = P @ V, V-tile of 128 columns, key tiles of 32
    float oacc[4][8] = {};
    const int v0 = vt * 128;
    const int vcol = tid & 127;
    const int vr0 = tid >> 7;
    for (int s0 = 0; s0 < 128; s0 += 32) {
        #pragma unroll
        for (int kr = vr0; kr < 32; kr += 2) {
            int kp = kpos0 + s0 + kr;
            int kpc = kp < 0 ? 0 : kp;
            float vv = x[(rowbase + kpc) * (size_t)H_ + v0 + vcol];
            Vt[kr][vcol] = (kp >= 0) ? vv : 0.f;
        }
        __syncthreads();
        #pragma unroll
        for (int k = 0; k < 32; ++k) {
            float a[4], bb[8];
            #pragma unroll
            for (int i = 0; i < 4; ++i) a[i] = Psh[ty * 4 + i][s0 + k];
            #pragma unroll
            for (int j = 0; j < 8; ++j) bb[j] = Vt[k][tx * 8 + j];
            #pragma unroll
            for (int i = 0; i < 4; ++i)
                #pragma unroll
                for (int j = 0; j < 8; ++j) oacc[i][j] += a[i] * bb[j];
        }
        __syncthreads();
    }
    #pragma unroll
    for (int i = 0; i < 4; ++i) {
        size_t m = rowbase + q0 + ty * 4 + i;
        #pragma unroll
        for (int j = 0; j < 8; ++j)
            o[m * H_ + v0 + tx * 8 + j] = oacc[i][j];
    }
}

// ---------------------------------------------------------------------------
// Kernel 4a: per-row rsqrt(mean(o^2)+eps)
// ---------------------------------------------------------------------------
__global__ __launch_bounds__(256) void row_rms_kernel(
    const float* __restrict__ o, float* __restrict__ rrms)
{
    const int m = blockIdx.x;
    const int tid = threadIdx.x;
    const float* row = o + (size_t)m * H_;
    float s = 0.f;
    for (int j = tid; j < H_; j += 256) { float v = row[j]; s += v * v; }
    #pragma unroll
    for (int d = 32; d > 0; d >>= 1) s += __shfl_down(s, d, 64);
    __shared__ float red[4];
    if ((tid & 63) == 0) red[tid >> 6] = s;
    __syncthreads();
    if (tid == 0)
        rrms[m] = rsqrtf((red[0] + red[1] + red[2] + red[3]) * (1.0f / H_) + EPS_);
}

// ---------------------------------------------------------------------------
// Kernel 4b: go = o @ Wog^T + x @ Wig^T ; out = (o*rrms*gw) * go * sigmoid(go)
// M=N=4096x2048, K=2048 (dual). 128x128 tile, 256 threads, 8x8 per thread.
// ---------------------------------------------------------------------------
__global__ __launch_bounds__(256) void out_gemm_kernel(
    const float* __restrict__ o, const float* __restrict__ x,
    const float* __restrict__ Wog, const float* __restrict__ Wig,
    const float* __restrict__ gw, const float* __restrict__ rrms,
    float* __restrict__ out)
{
    __shared__ float Ao[16][132];
    __shared__ float Ax[16][132];
    __shared__ float Bo[16][132];
    __shared__ float Bx[16][132];
    const int tid = threadIdx.x;
    const int tx = tid & 15, ty = tid >> 4;
    const int m0 = blockIdx.x * 128;
    const int n0 = blockIdx.y * 128;
    float acc[8][8] = {};
    const int kk = tid & 15;
    const int r0 = tid >> 4;
    for (int k0 = 0; k0 < H_; k0 += 16) {
        #pragma unroll
        for (int rit = 0; rit < 8; ++rit) {
            int r = r0 + rit * 16;
            size_t ai = (size_t)(m0 + r) * H_ + k0 + kk;
            size_t bi = (size_t)(n0 + r) * H_ + k0 + kk;
            Ao[kk][r] = o[ai];
            Ax[kk][r] = x[ai];
            Bo[kk][r] = Wog[bi];
            Bx[kk][r] = Wig[bi];
        }
        __syncthreads();
        #pragma unroll
        for (int k = 0; k < 16; ++k) {
            float a0[8], a1[8], b0[8], b1[8];
            #pragma unroll
            for (int i = 0; i < 8; ++i) { a0[i] = Ao[k][ty * 8 + i]; a1[i] = Ax[k][ty * 8 + i]; }
            #pragma unroll
            for (int j = 0; j < 8; ++j) { b0[j] = Bo[k][tx * 8 + j]; b1[j] = Bx[k][tx * 8 + j]; }
            #pragma unroll
            for (int i = 0; i < 8; ++i)
                #pragma unroll
                for (int j = 0; j < 8; ++j)
                    acc[i][j] += a0[i] * b0[j] + a1[i] * b1[j];
        }
        __syncthreads();
    }
    #pragma unroll
    for (int i = 0; i < 8; ++i) {
        int m = m0 + ty * 8 + i;
        float rv = rrms[m];
        #pragma unroll
        for (int j = 0; j < 8; ++j) {
            int n = n0 + tx * 8 + j;
            float govv = acc[i][j];
            float ov = o[(size_t)m * H_ + n];
            float rmsv = ov * rv * gw[n];
            out[(size_t)m * H_ + n] = rmsv * govv * sigmoidf_(govv);
        }
    }
}

// ---------------------------------------------------------------------------
extern "C" void kernel_launch(void* const* d_in, const int* in_sizes, int n_in,
                              void* d_out, int out_size, void* d_ws, size_t ws_size,
                              hipStream_t stream) {
    (void)in_sizes; (void)n_in; (void)out_size; (void)ws_size;
    const float* x   = (const float*)d_in[0];
    const float* Wq  = (const float*)d_in[1];
    const float* Wk  = (const float*)d_in[2];
    const float* Wog = (const float*)d_in[3];
    const float* Wig = (const float*)d_in[4];
    const float* gw  = (const float*)d_in[5];
    float* out = (float*)d_out;

    float* ws = (float*)d_ws;
    const size_t MK = (size_t)B_ * L_ * KD_;   // 524288
    const size_t MH = (size_t)B_ * L_ * H_;    // 8388608
    float* q  = ws;
    float* ks = q + MK;
    float* g  = ks + MK;
    float* G  = g + MK;
    float* o  = G + MK;
    float* rr = o + MH;
    // total ws use: 4*MK + MH + 4096 floats = ~42 MB

    qk_proj_kernel<<<dim3(64, 4), 256, 0, stream>>>(x, Wq, Wk, q, ks, g);
    gate_scan_kernel<<<dim3(KD_, B_), 64, 0, stream>>>(g, G);
    gla_attn_kernel<<<dim3(32, B_, 16), 256, 0, stream>>>(q, ks, G, x, o);
    row_rms_kernel<<<B_ * L_, 256, 0, stream>>>(o, rr);
    out_gemm_kernel<<<dim3(32, 16), 256, 0, stream>>>(o, x, Wog, Wig, gw, rr, out);
}

// Round 2
// 629.010 us; speedup vs baseline: 4.4903x; 4.4903x over previous
//
#include <hip/hip_runtime.h>
#include <math.h>

// Problem constants (B=2, L=2048, H=2048, K=H/NH=128)
#define B_ 2
#define L_ 2048
#define H_ 2048
#define KD_ 128
#define SCALE_ 0.08838834764831845f  // 128^-0.5
#define EPS_ 1e-5f
#define K2_ 4096                     // concat-K for the dual output GEMM

typedef __bf16 bf16x8 __attribute__((ext_vector_type(8)));
typedef float f32x4 __attribute__((ext_vector_type(4)));

static __device__ __forceinline__ float sigmoidf_(float z) {
    return 1.0f / (1.0f + __expf(-z));
}

static __device__ __forceinline__ unsigned short f2bf(float f) {
    unsigned int u = __float_as_uint(f);
    unsigned int r = (u + 0x7fffu + ((u >> 16) & 1u)) >> 16;
    return (unsigned short)r;
}

// async global->LDS, 16B per lane; lds base must be wave-uniform
#define ASYNC_COPY16(gsrc, ldst)                                             \
    __builtin_amdgcn_global_load_lds(                                        \
        (const __attribute__((address_space(1))) unsigned int*)(gsrc),       \
        (__attribute__((address_space(3))) unsigned int*)(ldst), 16, 0, 0)

// ---------------------------------------------------------------------------
// Kernel 1: q_raw = x @ Wq^T, k_raw = x @ Wk^T  (M=4096, N=256, K=2048)
//   epilogue: q = silu(q_raw)*SCALE ; ks = sigmoid(k_raw) ; g = -log1p(exp(ks))
// ---------------------------------------------------------------------------
__global__ __launch_bounds__(256) void qk_proj_kernel(
    const float* __restrict__ x, const float* __restrict__ Wq,
    const float* __restrict__ Wk, float* __restrict__ q,
    float* __restrict__ ks, float* __restrict__ g)
{
    __shared__ float As[16][65];
    __shared__ float Bs[16][65];
    const int tid = threadIdx.x;
    const int tx = tid & 15, ty = tid >> 4;
    const int m0 = blockIdx.x * 64;
    const int n0 = blockIdx.y * 64;
    float acc[4][4] = {};
    const int kk = tid & 15;
    const int rr = tid >> 4;
    for (int k0 = 0; k0 < H_; k0 += 16) {
        #pragma unroll
        for (int rit = 0; rit < 4; ++rit) {
            int r = rr + rit * 16;
            As[kk][r] = x[(size_t)(m0 + r) * H_ + k0 + kk];
            int n = n0 + r;
            const float* Wrow = (n < KD_) ? (Wq + (size_t)n * H_)
                                          : (Wk + (size_t)(n - KD_) * H_);
            Bs[kk][r] = Wrow[k0 + kk];
        }
        __syncthreads();
        #pragma unroll
        for (int k = 0; k < 16; ++k) {
            float a[4], b[4];
            #pragma unroll
            for (int i = 0; i < 4; ++i) a[i] = As[k][ty * 4 + i];
            #pragma unroll
            for (int j = 0; j < 4; ++j) b[j] = Bs[k][tx * 4 + j];
            #pragma unroll
            for (int i = 0; i < 4; ++i)
                #pragma unroll
                for (int j = 0; j < 4; ++j) acc[i][j] += a[i] * b[j];
        }
        __syncthreads();
    }
    #pragma unroll
    for (int i = 0; i < 4; ++i) {
        int m = m0 + ty * 4 + i;
        #pragma unroll
        for (int j = 0; j < 4; ++j) {
            int n = n0 + tx * 4 + j;
            float v = acc[i][j];
            if (n < KD_) {
                q[(size_t)m * KD_ + n] = v * sigmoidf_(v) * SCALE_;
            } else {
                float sk = sigmoidf_(v);
                ks[(size_t)m * KD_ + (n - KD_)] = sk;
                g[(size_t)m * KD_ + (n - KD_)] = -log1pf(__expf(sk));
            }
        }
    }
}

// ---------------------------------------------------------------------------
// Kernel 2: inclusive prefix sum of g along L per (batch, key-dim).
// ---------------------------------------------------------------------------
__global__ __launch_bounds__(64) void gate_scan_kernel(
    const float* __restrict__ g, float* __restrict__ G)
{
    const int kd = blockIdx.x;
    const int b  = blockIdx.y;
    const int lane = threadIdx.x;
    const float* gp = g + (size_t)b * L_ * KD_ + kd;
    float* Gp = G + (size_t)b * L_ * KD_ + kd;
    float vals[32];
    float s = 0.f;
    const int t0 = lane * 32;
    #pragma unroll
    for (int j = 0; j < 32; ++j) { s += gp[(size_t)(t0 + j) * KD_]; vals[j] = s; }
    float incl = s;
    #pragma unroll
    for (int d = 1; d < 64; d <<= 1) {
        float n = __shfl_up(incl, d, 64);
        if (lane >= d) incl += n;
    }
    float excl = incl - s;
    #pragma unroll
    for (int j = 0; j < 32; ++j) Gp[(size_t)(t0 + j) * KD_] = excl + vals[j];
}

// ---------------------------------------------------------------------------
// Kernel 3: banded GLA attention (decay <= 0.5/step => band of 128 suffices;
// truncation error < 0.5^65, far below the 0.38 threshold).
// ---------------------------------------------------------------------------
__global__ __launch_bounds__(256) void gla_attn_kernel(
    const float* __restrict__ q, const float* __restrict__ ks,
    const float* __restrict__ G, const float* __restrict__ x,
    float* __restrict__ o)
{
    const int c  = blockIdx.x;  // 0..31
    const int b  = blockIdx.y;  // 0..1
    const int vt = blockIdx.z;  // 0..15
    const int tid = threadIdx.x;
    const int tx = tid & 15, ty = tid >> 4;

    __shared__ float uni[6336];
    float (*qt)[33]  = (float(*)[33])uni;
    float (*kt)[33]  = (float(*)[33])(uni + 64 * 33);
    float (*Vt)[128] = (float(*)[128])uni;
    __shared__ float Psh[64][128];
    __shared__ float Rsh[128];

    const int q0 = c * 64;
    const int kpos0 = q0 - 64;
    const size_t rowbase = (size_t)b * L_;

    if (tid < 128)
        Rsh[tid] = (c > 0) ? G[(rowbase + q0 - 1) * KD_ + tid] : 0.f;
    __syncthreads();

    float acc[4][8] = {};
    const int skk = tid & 31;
    const int sr0 = tid >> 5;
    for (int k0 = 0; k0 < KD_; k0 += 32) {
        float Rv = Rsh[k0 + skk];
        #pragma unroll
        for (int r = sr0; r < 64; r += 8) {
            size_t idx = (rowbase + q0 + r) * (size_t)KD_ + k0 + skk;
            qt[r][skk] = q[idx] * __expf(G[idx] - Rv);
        }
        #pragma unroll
        for (int r = sr0; r < 128; r += 8) {
            int kp = kpos0 + r;
            float val = 0.f;
            if (kp >= 0) {
                size_t idx = (rowbase + kp) * (size_t)KD_ + k0 + skk;
                val = ks[idx] * __expf(Rv - G[idx]);
            }
            kt[r][skk] = val;
        }
        __syncthreads();
        #pragma unroll
        for (int k = 0; k < 32; ++k) {
            float a[4], bb[8];
            #pragma unroll
            for (int i = 0; i < 4; ++i) a[i] = qt[ty * 4 + i][k];
            #pragma unroll
            for (int j = 0; j < 8; ++j) bb[j] = kt[tx * 8 + j][k];
            #pragma unroll
            for (int i = 0; i < 4; ++i)
                #pragma unroll
                for (int j = 0; j < 8; ++j) acc[i][j] += a[i] * bb[j];
        }
        __syncthreads();
    }
    #pragma unroll
    for (int i = 0; i < 4; ++i) {
        int ti = ty * 4 + i;
        #pragma unroll
        for (int j = 0; j < 8; ++j) {
            int si = tx * 8 + j;
            int kp = kpos0 + si;
            Psh[ti][si] = (kp >= 0 && si <= ti + 64) ? acc[i][j] : 0.f;
        }
    }
    __syncthreads();

    float oacc[4][8] = {};
    const int v0 = vt * 128;
    const int vcol = tid & 127;
    const int vr0 = tid >> 7;
    for (int s0 = 0; s0 < 128; s0 += 32) {
        #pragma unroll
        for (int kr = vr0; kr < 32; kr += 2) {
            int kp = kpos0 + s0 + kr;
            int kpc = kp < 0 ? 0 : kp;
            float vv = x[(rowbase + kpc) * (size_t)H_ + v0 + vcol];
            Vt[kr][vcol] = (kp >= 0) ? vv : 0.f;
        }
        __syncthreads();
        #pragma unroll
        for (int k = 0; k < 32; ++k) {
            float a[4], bb[8];
            #pragma unroll
            for (int i = 0; i < 4; ++i) a[i] = Psh[ty * 4 + i][s0 + k];
            #pragma unroll
            for (int j = 0; j < 8; ++j) bb[j] = Vt[k][tx * 8 + j];
            #pragma unroll
            for (int i = 0; i < 4; ++i)
                #pragma unroll
                for (int j = 0; j < 8; ++j) oacc[i][j] += a[i] * bb[j];
        }
        __syncthreads();
    }
    #pragma unroll
    for (int i = 0; i < 4; ++i) {
        size_t m = rowbase + q0 + ty * 4 + i;
        #pragma unroll
        for (int j = 0; j < 8; ++j)
            o[m * H_ + v0 + tx * 8 + j] = oacc[i][j];
    }
}

// ---------------------------------------------------------------------------
// Kernel 4a: per-row rsqrt(mean(o^2)+eps)
// ---------------------------------------------------------------------------
__global__ __launch_bounds__(256) void row_rms_kernel(
    const float* __restrict__ o, float* __restrict__ rrms)
{
    const int m = blockIdx.x;
    const int tid = threadIdx.x;
    const float* row = o + (size_t)m * H_;
    float s = 0.f;
    for (int j = tid; j < H_; j += 256) { float v = row[j]; s += v * v; }
    #pragma unroll
    for (int d = 32; d > 0; d >>= 1) s += __shfl_down(s, d, 64);
    __shared__ float red[4];
    if ((tid & 63) == 0) red[tid >> 6] = s;
    __syncthreads();
    if (tid == 0)
        rrms[m] = rsqrtf((red[0] + red[1] + red[2] + red[3]) * (1.0f / H_) + EPS_);
}

// ---------------------------------------------------------------------------
// Kernel 4b-prep: cast/concat A = [o | x] -> bf16 [4096][4096]
// ---------------------------------------------------------------------------
__global__ __launch_bounds__(256) void cast_concat_A(
    const float* __restrict__ o, const float* __restrict__ x,
    unsigned short* __restrict__ Abuf)
{
    size_t i = (size_t)blockIdx.x * 256 + threadIdx.x;   // group of 4 floats
    const size_t half = (size_t)4096 * 512;              // 4096 rows x 512 groups
    const float* src = (i < half) ? o : x;
    size_t j = (i < half) ? i : i - half;
    size_t m = j >> 9;
    size_t c4 = (j & 511) * 4;
    float4 v = *(const float4*)(src + m * H_ + c4);
    ushort4 bb;
    bb.x = f2bf(v.x); bb.y = f2bf(v.y); bb.z = f2bf(v.z); bb.w = f2bf(v.w);
    size_t off = (i < half) ? 0 : H_;
    *(ushort4*)(Abuf + m * K2_ + off + c4) = bb;
}

// Kernel 4b-prep: cast/concat B = [Wog | Wig] -> bf16 [2048][4096]
__global__ __launch_bounds__(256) void cast_concat_B(
    const float* __restrict__ Wog, const float* __restrict__ Wig,
    unsigned short* __restrict__ Bbuf)
{
    size_t i = (size_t)blockIdx.x * 256 + threadIdx.x;
    const size_t half = (size_t)2048 * 512;
    const float* src = (i < half) ? Wog : Wig;
    size_t j = (i < half) ? i : i - half;
    size_t n = j >> 9;
    size_t c4 = (j & 511) * 4;
    float4 v = *(const float4*)(src + n * H_ + c4);
    ushort4 bb;
    bb.x = f2bf(v.x); bb.y = f2bf(v.y); bb.z = f2bf(v.z); bb.w = f2bf(v.w);
    size_t off = (i < half) ? 0 : H_;
    *(ushort4*)(Bbuf + n * K2_ + off + c4) = bb;
}

// ---------------------------------------------------------------------------
// Kernel 4b: go = A @ B^T via bf16 MFMA (m97 structure: 128x128 tile,
// 16x16x32 MFMA, global_load_lds width 16, BK=64, 2-barrier K-loop).
// Fused epilogue: out = (o*rrms*gw) * go * sigmoid(go).
// M=4096, N=2048, K=4096.
// ---------------------------------------------------------------------------
__global__ __launch_bounds__(256) void out_gemm_mfma(
    const unsigned short* __restrict__ Abuf,
    const unsigned short* __restrict__ Bbuf,
    const float* __restrict__ o, const float* __restrict__ gw,
    const float* __restrict__ rrms, float* __restrict__ out)
{
    __shared__ alignas(16) unsigned short As[128 * 64];  // [row][64] packed
    __shared__ alignas(16) unsigned short Bs[128 * 64];
    const int tid  = threadIdx.x;
    const int wave = tid >> 6;
    const int lane = tid & 63;
    const int m0 = blockIdx.x * 128;
    const int n0 = blockIdx.y * 128;
    const int wm = (wave >> 1) * 64;   // wave's 64x64 subtile
    const int wn = (wave & 1) * 64;

    f32x4 acc[4][4] = {};

    // staging geometry: per instr a wave moves 64 lanes x 16B = 8 rows of 64
    const int se  = lane * 8;                 // element offset within the 512-elem chunk
    const int ldsbase = (wave * 4) * 512;     // this wave's first chunk (elements)

    const int frow = lane & 15;               // fragment row within 16
    const int fk   = (lane >> 4) * 8;         // fragment k offset within 32

    for (int k0 = 0; k0 < K2_; k0 += 64) {
        #pragma unroll
        for (int it = 0; it < 4; ++it) {
            int e = ldsbase + it * 512 + se;  // element index in 128x64 tile
            int r = e >> 6, cc = e & 63;
            const unsigned short* ga = Abuf + (size_t)(m0 + r) * K2_ + k0 + cc;
            ASYNC_COPY16(ga, &As[e]);
            const unsigned short* gb = Bbuf + (size_t)(n0 + r) * K2_ + k0 + cc;
            ASYNC_COPY16(gb, &Bs[e]);
        }
        __syncthreads();
        #pragma unroll
        for (int ksub = 0; ksub < 2; ++ksub) {
            bf16x8 af[4], bf[4];
            #pragma unroll
            for (int i = 0; i < 4; ++i)
                af[i] = *(const bf16x8*)(As + (wm + i * 16 + frow) * 64 + ksub * 32 + fk);
            #pragma unroll
            for (int j = 0; j < 4; ++j)
                bf[j] = *(const bf16x8*)(Bs + (wn + j * 16 + frow) * 64 + ksub * 32 + fk);
            #pragma unroll
            for (int i = 0; i < 4; ++i)
                #pragma unroll
                for (int j = 0; j < 4; ++j)
                    acc[i][j] = __builtin_amdgcn_mfma_f32_16x16x32_bf16(
                        af[i], bf[j], acc[i][j], 0, 0, 0);
        }
        __syncthreads();
    }

    // Epilogue: D row = wm + i*16 + (lane>>4)*4 + reg ; col = wn + j*16 + (lane&15)
    #pragma unroll
    for (int i = 0; i < 4; ++i) {
        #pragma unroll
        for (int reg = 0; reg < 4; ++reg) {
            int m = m0 + wm + i * 16 + (lane >> 4) * 4 + reg;
            float rv = rrms[m];
            #pragma unroll
            for (int j = 0; j < 4; ++j) {
                int n = n0 + wn + j * 16 + (lane & 15);
                float go = acc[i][j][reg];
                float ov = o[(size_t)m * H_ + n];
                out[(size_t)m * H_ + n] = ov * rv * gw[n] * go * sigmoidf_(go);
            }
        }
    }
}

// ---------------------------------------------------------------------------
extern "C" void kernel_launch(void* const* d_in, const int* in_sizes, int n_in,
                              void* d_out, int out_size, void* d_ws, size_t ws_size,
                              hipStream_t stream) {
    (void)in_sizes; (void)n_in; (void)out_size; (void)ws_size;
    const float* x   = (const float*)d_in[0];
    const float* Wq  = (const float*)d_in[1];
    const float* Wk  = (const float*)d_in[2];
    const float* Wog = (const float*)d_in[3];
    const float* Wig = (const float*)d_in[4];
    const float* gw  = (const float*)d_in[5];
    float* out = (float*)d_out;

    float* ws = (float*)d_ws;
    const size_t MK = (size_t)B_ * L_ * KD_;   // 524288
    const size_t MH = (size_t)B_ * L_ * H_;    // 8388608
    float* q  = ws;
    float* ks = q + MK;
    float* g  = ks + MK;
    float* G  = g + MK;
    float* o  = G + MK;
    float* rr = o + MH;
    unsigned short* Abuf = (unsigned short*)(rr + 4096);   // [4096][4096] bf16
    unsigned short* Bbuf = Abuf + (size_t)4096 * K2_;      // [2048][4096] bf16
    // ws use: ~42 MB fp32 + 32 MB + 16 MB bf16 = ~90 MB

    qk_proj_kernel<<<dim3(64, 4), 256, 0, stream>>>(x, Wq, Wk, q, ks, g);
    gate_scan_kernel<<<dim3(KD_, B_), 64, 0, stream>>>(g, G);
    cast_concat_B<<<8192, 256, 0, stream>>>(Wog, Wig, Bbuf);
    gla_attn_kernel<<<dim3(32, B_, 16), 256, 0, stream>>>(q, ks, G, x, o);
    row_rms_kernel<<<B_ * L_, 256, 0, stream>>>(o, rr);
    cast_concat_A<<<16384, 256, 0, stream>>>(o, x, Abuf);
    out_gemm_mfma<<<dim3(32, 16), 256, 0, stream>>>(Abuf, Bbuf, o, gw, rr, out);
}

// Round 3
// 429.360 us; speedup vs baseline: 6.5782x; 1.4650x over previous
//
#include <hip/hip_runtime.h>
#include <math.h>

// Problem constants (B=2, L=2048, H=2048, K=H/NH=128)
#define B_ 2
#define L_ 2048
#define H_ 2048
#define KD_ 128
#define SCALE_ 0.08838834764831845f  // 128^-0.5
#define EPS_ 1e-5f
#define K2_ 4096                     // concat-K for the dual output GEMM

typedef __bf16 bf16x8 __attribute__((ext_vector_type(8)));
typedef float f32x4 __attribute__((ext_vector_type(4)));

static __device__ __forceinline__ float sigmoidf_(float z) {
    return 1.0f / (1.0f + __expf(-z));
}

static __device__ __forceinline__ unsigned short f2bf(float f) {
    unsigned int u = __float_as_uint(f);
    unsigned int r = (u + 0x7fffu + ((u >> 16) & 1u)) >> 16;
    return (unsigned short)r;
}

// async global->LDS, 16B per lane; lds base must be wave-uniform
#define ASYNC_COPY16(gsrc, ldst)                                             \
    __builtin_amdgcn_global_load_lds(                                        \
        (const __attribute__((address_space(1))) unsigned int*)(gsrc),       \
        (__attribute__((address_space(3))) unsigned int*)(ldst), 16, 0, 0)

// ---------------------------------------------------------------------------
// Kernel 1: q_raw = x @ Wq^T, k_raw = x @ Wk^T  (M=4096, N=256, K=2048)
//   epilogue: q = silu(q_raw)*SCALE ; ks = sigmoid(k_raw) ; g = -log1p(exp(ks))
// ---------------------------------------------------------------------------
__global__ __launch_bounds__(256) void qk_proj_kernel(
    const float* __restrict__ x, const float* __restrict__ Wq,
    const float* __restrict__ Wk, float* __restrict__ q,
    float* __restrict__ ks, float* __restrict__ g)
{
    __shared__ float As[16][65];
    __shared__ float Bs[16][65];
    const int tid = threadIdx.x;
    const int tx = tid & 15, ty = tid >> 4;
    const int m0 = blockIdx.x * 64;
    const int n0 = blockIdx.y * 64;
    float acc[4][4] = {};
    const int kk = tid & 15;
    const int rr = tid >> 4;
    for (int k0 = 0; k0 < H_; k0 += 16) {
        #pragma unroll
        for (int rit = 0; rit < 4; ++rit) {
            int r = rr + rit * 16;
            As[kk][r] = x[(size_t)(m0 + r) * H_ + k0 + kk];
            int n = n0 + r;
            const float* Wrow = (n < KD_) ? (Wq + (size_t)n * H_)
                                          : (Wk + (size_t)(n - KD_) * H_);
            Bs[kk][r] = Wrow[k0 + kk];
        }
        __syncthreads();
        #pragma unroll
        for (int k = 0; k < 16; ++k) {
            float a[4], b[4];
            #pragma unroll
            for (int i = 0; i < 4; ++i) a[i] = As[k][ty * 4 + i];
            #pragma unroll
            for (int j = 0; j < 4; ++j) b[j] = Bs[k][tx * 4 + j];
            #pragma unroll
            for (int i = 0; i < 4; ++i)
                #pragma unroll
                for (int j = 0; j < 4; ++j) acc[i][j] += a[i] * b[j];
        }
        __syncthreads();
    }
    #pragma unroll
    for (int i = 0; i < 4; ++i) {
        int m = m0 + ty * 4 + i;
        #pragma unroll
        for (int j = 0; j < 4; ++j) {
            int n = n0 + tx * 4 + j;
            float v = acc[i][j];
            if (n < KD_) {
                q[(size_t)m * KD_ + n] = v * sigmoidf_(v) * SCALE_;
            } else {
                float sk = sigmoidf_(v);
                ks[(size_t)m * KD_ + (n - KD_)] = sk;
                g[(size_t)m * KD_ + (n - KD_)] = -log1pf(__expf(sk));
            }
        }
    }
}

// ---------------------------------------------------------------------------
// Kernel 2: inclusive prefix sum of g along L per (batch, key-dim).
// ---------------------------------------------------------------------------
__global__ __launch_bounds__(64) void gate_scan_kernel(
    const float* __restrict__ g, float* __restrict__ G)
{
    const int kd = blockIdx.x;
    const int b  = blockIdx.y;
    const int lane = threadIdx.x;
    const float* gp = g + (size_t)b * L_ * KD_ + kd;
    float* Gp = G + (size_t)b * L_ * KD_ + kd;
    float vals[32];
    float s = 0.f;
    const int t0 = lane * 32;
    #pragma unroll
    for (int j = 0; j < 32; ++j) { s += gp[(size_t)(t0 + j) * KD_]; vals[j] = s; }
    float incl = s;
    #pragma unroll
    for (int d = 1; d < 64; d <<= 1) {
        float n = __shfl_up(incl, d, 64);
        if (lane >= d) incl += n;
    }
    float excl = incl - s;
    #pragma unroll
    for (int j = 0; j < 32; ++j) Gp[(size_t)(t0 + j) * KD_] = excl + vals[j];
}

// ---------------------------------------------------------------------------
// Kernel 3a: chunk-referenced scaled q/k in bf16.
//   For row t (chunk c = t>>6, R1 = G[c*64-1], R2 = G[c*64+63]):
//     qt = q * exp(G - R1)          (<= q, down to e^-84 ~ 3e-37: bf16-normal)
//     kA = ks * exp(R1 - G)         (up to e^84 ~ 3e36 < bf16 max 3.4e38)
//     kB = ks * exp(R2 - G)         (<= ks; zero for the last chunk)
// ---------------------------------------------------------------------------
__global__ __launch_bounds__(256) void qk_scale_kernel(
    const float* __restrict__ q, const float* __restrict__ ks,
    const float* __restrict__ G, unsigned short* __restrict__ qt_b,
    unsigned short* __restrict__ kA_b, unsigned short* __restrict__ kB_b)
{
    const int tid = threadIdx.x;
    const int r = blockIdx.x * 16 + (tid >> 4);      // 0..4095
    const int d0 = (tid & 15) * 8;
    const int t = r & (L_ - 1);
    const bool has_prev = (t >= 64);
    const bool last = ((t >> 6) == (L_ / 64 - 1));
    const size_t base = (size_t)r * KD_ + d0;
    const size_t r1base = (size_t)((r & ~63) - 1) * KD_ + d0;
    const size_t r2base = (size_t)(r | 63) * KD_ + d0;

    float qv[8], kv[8], Gv[8], R1[8], R2[8];
    *(float4*)(qv)     = *(const float4*)(q + base);
    *(float4*)(qv + 4) = *(const float4*)(q + base + 4);
    *(float4*)(kv)     = *(const float4*)(ks + base);
    *(float4*)(kv + 4) = *(const float4*)(ks + base + 4);
    *(float4*)(Gv)     = *(const float4*)(G + base);
    *(float4*)(Gv + 4) = *(const float4*)(G + base + 4);
    if (has_prev) {
        *(float4*)(R1)     = *(const float4*)(G + r1base);
        *(float4*)(R1 + 4) = *(const float4*)(G + r1base + 4);
    } else {
        #pragma unroll
        for (int j = 0; j < 8; ++j) R1[j] = 0.f;
    }
    if (!last) {
        *(float4*)(R2)     = *(const float4*)(G + r2base);
        *(float4*)(R2 + 4) = *(const float4*)(G + r2base + 4);
    }
    unsigned short oq[8], oa[8], ob[8];
    #pragma unroll
    for (int j = 0; j < 8; ++j) {
        oq[j] = f2bf(qv[j] * __expf(Gv[j] - R1[j]));
        oa[j] = f2bf(kv[j] * __expf(R1[j] - Gv[j]));
        ob[j] = last ? (unsigned short)0 : f2bf(kv[j] * __expf(R2[j] - Gv[j]));
    }
    *(ushort4*)(qt_b + base)     = *(ushort4*)(oq);
    *(ushort4*)(qt_b + base + 4) = *(ushort4*)(oq + 4);
    *(ushort4*)(kA_b + base)     = *(ushort4*)(oa);
    *(ushort4*)(kA_b + base + 4) = *(ushort4*)(oa + 4);
    *(ushort4*)(kB_b + base)     = *(ushort4*)(ob);
    *(ushort4*)(kB_b + base + 4) = *(ushort4*)(ob + 4);
}

// ---------------------------------------------------------------------------
// Kernel 3b (prep): cast x -> bf16 into the x-half of Abuf (cols 2048..4095).
// ---------------------------------------------------------------------------
__global__ __launch_bounds__(256) void cast_x_half(
    const float* __restrict__ x, unsigned short* __restrict__ Abuf)
{
    size_t i = (size_t)blockIdx.x * 256 + threadIdx.x;   // group of 8 floats
    size_t m = i >> 8;
    size_t c8 = (i & 255) * 8;
    float4 v0 = *(const float4*)(x + m * H_ + c8);
    float4 v1 = *(const float4*)(x + m * H_ + c8 + 4);
    ushort4 a, b;
    a.x = f2bf(v0.x); a.y = f2bf(v0.y); a.z = f2bf(v0.z); a.w = f2bf(v0.w);
    b.x = f2bf(v1.x); b.y = f2bf(v1.y); b.z = f2bf(v1.z); b.w = f2bf(v1.w);
    unsigned short* dst = Abuf + m * K2_ + H_ + c8;
    *(ushort4*)dst = a;
    *(ushort4*)(dst + 4) = b;
}

// ---------------------------------------------------------------------------
// Kernel 3c: banded GLA attention, all-MFMA.
// Phase 1: P[64q x 128keys] = qt . k~^T  (K=128 dims), mask, -> Psh bf16.
// Phase 2: O[64 x 128vcols] = P @ V (V = bf16 x rows, staged transposed in
// LDS so the MFMA B-operand [n][k] layout reads contiguously).
// Writes o fp32 and the bf16 o-half of Abuf.
// ---------------------------------------------------------------------------
#define SV_ 130   // Vt row stride (elems): 4-way write conflict, 4B-aligned reads
#define SP_ 136   // Psh row stride (elems): 16B-aligned rows, conflict-free

__global__ __launch_bounds__(256) void gla_attn_mfma(
    const unsigned short* __restrict__ qt_b,
    const unsigned short* __restrict__ kA_b,
    const unsigned short* __restrict__ kB_b,
    unsigned short* Abuf,          // reads x-half (cols 2048+), writes o-half
    float* __restrict__ o)
{
    const int c  = blockIdx.x;   // chunk 0..31
    const int b  = blockIdx.y;
    const int vt = blockIdx.z;   // 0..15
    const int tid = threadIdx.x;
    const int w = tid >> 6, l = tid & 63;
    const int lr = l & 15, lq = l >> 4;
    const int q0 = c * 64, kpos0 = q0 - 64, v0c = vt * 128;
    const size_t rowbase = (size_t)b * L_;

    __shared__ alignas(16) unsigned short Vt[128 * SV_];
    __shared__ alignas(16) unsigned short Psh[64 * SP_];

    // ---- stage V transposed: Vt[vcol][key] ----
    {
        const int a = tid & 15;       // col group (8 cols)
        const int kr0 = tid >> 4;
        for (int kr = kr0; kr < 128; kr += 16) {
            int kp = kpos0 + kr;
            ushort4 u0 = {0, 0, 0, 0}, u1 = {0, 0, 0, 0};
            if (kp >= 0) {
                const unsigned short* src =
                    Abuf + (rowbase + kp) * K2_ + H_ + v0c + a * 8;
                u0 = *(const ushort4*)src;
                u1 = *(const ushort4*)(src + 4);
            }
            unsigned short vals[8] = {u0.x, u0.y, u0.z, u0.w,
                                      u1.x, u1.y, u1.z, u1.w};
            #pragma unroll
            for (int j = 0; j < 8; ++j)
                Vt[(a * 8 + j) * SV_ + kr] = vals[j];
        }
    }

    // ---- phase 1: P = qt . k~^T ----
    bf16x8 aq[4];
    {
        const unsigned short* qrow = qt_b + (rowbase + q0 + 16 * w + lr) * KD_;
        #pragma unroll
        for (int kt = 0; kt < 4; ++kt)
            aq[kt] = *(const bf16x8*)(qrow + kt * 32 + lq * 8);
    }
    #pragma unroll
    for (int jt = 0; jt < 8; ++jt) {
        f32x4 p = {};
        const int si = jt * 16 + lr;          // window key index 0..127
        const bool prev = (jt < 4);
        const bool dead = (c == 0 && prev);   // keys before t=0
        if (!dead) {
            int kp = prev ? (kpos0 + si) : (q0 + si - 64);
            const unsigned short* kb = (prev ? kB_b : kA_b) + (rowbase + kp) * KD_;
            #pragma unroll
            for (int kt = 0; kt < 4; ++kt) {
                bf16x8 bk = *(const bf16x8*)(kb + kt * 32 + lq * 8);
                p = __builtin_amdgcn_mfma_f32_16x16x32_bf16(aq[kt], bk, p, 0, 0, 0);
            }
        }
        #pragma unroll
        for (int reg = 0; reg < 4; ++reg) {
            int ti = 16 * w + lq * 4 + reg;   // q row 0..63
            bool keep = !dead && (si <= ti + 64);   // causal band
            Psh[ti * SP_ + si] = keep ? f2bf(p[reg]) : (unsigned short)0;
        }
    }
    __syncthreads();

    // ---- phase 2: O = P @ V ----
    bf16x8 ap[4];
    #pragma unroll
    for (int kt = 0; kt < 4; ++kt)
        ap[kt] = *(const bf16x8*)(Psh + (16 * w + lr) * SP_ + kt * 32 + lq * 8);
    #pragma unroll
    for (int jt = 0; jt < 8; ++jt) {
        f32x4 oa = {};
        const int n = jt * 16 + lr;           // vcol within tile
        #pragma unroll
        for (int kt = 0; kt < 4; ++kt) {
            const unsigned int* vp =
                (const unsigned int*)(Vt + n * SV_ + kt * 32 + lq * 8);
            union { unsigned int u[4]; bf16x8 v; } bb;
            bb.u[0] = vp[0]; bb.u[1] = vp[1]; bb.u[2] = vp[2]; bb.u[3] = vp[3];
            oa = __builtin_amdgcn_mfma_f32_16x16x32_bf16(ap[kt], bb.v, oa, 0, 0, 0);
        }
        #pragma unroll
        for (int reg = 0; reg < 4; ++reg) {
            int qrow = 16 * w + lq * 4 + reg;
            size_t orow = rowbase + q0 + qrow;
            float val = oa[reg];
            o[orow * H_ + v0c + n] = val;
            Abuf[orow * K2_ + v0c + n] = f2bf(val);
        }
    }
}

// ---------------------------------------------------------------------------
// Kernel 4a: per-row rsqrt(mean(o^2)+eps)
// ---------------------------------------------------------------------------
__global__ __launch_bounds__(256) void row_rms_kernel(
    const float* __restrict__ o, float* __restrict__ rrms)
{
    const int m = blockIdx.x;
    const int tid = threadIdx.x;
    const float* row = o + (size_t)m * H_;
    float s = 0.f;
    for (int j = tid; j < H_; j += 256) { float v = row[j]; s += v * v; }
    #pragma unroll
    for (int d = 32; d > 0; d >>= 1) s += __shfl_down(s, d, 64);
    __shared__ float red[4];
    if ((tid & 63) == 0) red[tid >> 6] = s;
    __syncthreads();
    if (tid == 0)
        rrms[m] = rsqrtf((red[0] + red[1] + red[2] + red[3]) * (1.0f / H_) + EPS_);
}

// Kernel 4b-prep: cast/concat B = [Wog | Wig] -> bf16 [2048][4096]
__global__ __launch_bounds__(256) void cast_concat_B(
    const float* __restrict__ Wog, const float* __restrict__ Wig,
    unsigned short* __restrict__ Bbuf)
{
    size_t i = (size_t)blockIdx.x * 256 + threadIdx.x;
    const size_t half = (size_t)2048 * 512;
    const float* src = (i < half) ? Wog : Wig;
    size_t j = (i < half) ? i : i - half;
    size_t n = j >> 9;
    size_t c4 = (j & 511) * 4;
    float4 v = *(const float4*)(src + n * H_ + c4);
    ushort4 bb;
    bb.x = f2bf(v.x); bb.y = f2bf(v.y); bb.z = f2bf(v.z); bb.w = f2bf(v.w);
    size_t off = (i < half) ? 0 : H_;
    *(ushort4*)(Bbuf + n * K2_ + off + c4) = bb;
}

// ---------------------------------------------------------------------------
// Kernel 4b: go = A @ B^T via bf16 MFMA (m97 structure). Fused epilogue:
// out = (o*rrms*gw) * go * sigmoid(go).  M=4096, N=2048, K=4096.
// ---------------------------------------------------------------------------
__global__ __launch_bounds__(256) void out_gemm_mfma(
    const unsigned short* __restrict__ Abuf,
    const unsigned short* __restrict__ Bbuf,
    const float* __restrict__ o, const float* __restrict__ gw,
    const float* __restrict__ rrms, float* __restrict__ out)
{
    __shared__ alignas(16) unsigned short As[128 * 64];
    __shared__ alignas(16) unsigned short Bs[128 * 64];
    const int tid  = threadIdx.x;
    const int wave = tid >> 6;
    const int lane = tid & 63;
    const int m0 = blockIdx.x * 128;
    const int n0 = blockIdx.y * 128;
    const int wm = (wave >> 1) * 64;
    const int wn = (wave & 1) * 64;

    f32x4 acc[4][4] = {};

    const int se  = lane * 8;
    const int ldsbase = (wave * 4) * 512;
    const int frow = lane & 15;
    const int fk   = (lane >> 4) * 8;

    for (int k0 = 0; k0 < K2_; k0 += 64) {
        #pragma unroll
        for (int it = 0; it < 4; ++it) {
            int e = ldsbase + it * 512 + se;
            int r = e >> 6, cc = e & 63;
            const unsigned short* ga = Abuf + (size_t)(m0 + r) * K2_ + k0 + cc;
            ASYNC_COPY16(ga, &As[e]);
            const unsigned short* gb = Bbuf + (size_t)(n0 + r) * K2_ + k0 + cc;
            ASYNC_COPY16(gb, &Bs[e]);
        }
        __syncthreads();
        #pragma unroll
        for (int ksub = 0; ksub < 2; ++ksub) {
            bf16x8 af[4], bf[4];
            #pragma unroll
            for (int i = 0; i < 4; ++i)
                af[i] = *(const bf16x8*)(As + (wm + i * 16 + frow) * 64 + ksub * 32 + fk);
            #pragma unroll
            for (int j = 0; j < 4; ++j)
                bf[j] = *(const bf16x8*)(Bs + (wn + j * 16 + frow) * 64 + ksub * 32 + fk);
            #pragma unroll
            for (int i = 0; i < 4; ++i)
                #pragma unroll
                for (int j = 0; j < 4; ++j)
                    acc[i][j] = __builtin_amdgcn_mfma_f32_16x16x32_bf16(
                        af[i], bf[j], acc[i][j], 0, 0, 0);
        }
        __syncthreads();
    }

    #pragma unroll
    for (int i = 0; i < 4; ++i) {
        #pragma unroll
        for (int reg = 0; reg < 4; ++reg) {
            int m = m0 + wm + i * 16 + (lane >> 4) * 4 + reg;
            float rv = rrms[m];
            #pragma unroll
            for (int j = 0; j < 4; ++j) {
                int n = n0 + wn + j * 16 + (lane & 15);
                float go = acc[i][j][reg];
                float ov = o[(size_t)m * H_ + n];
                out[(size_t)m * H_ + n] = ov * rv * gw[n] * go * sigmoidf_(go);
            }
        }
    }
}

// ---------------------------------------------------------------------------
extern "C" void kernel_launch(void* const* d_in, const int* in_sizes, int n_in,
                              void* d_out, int out_size, void* d_ws, size_t ws_size,
                              hipStream_t stream) {
    (void)in_sizes; (void)n_in; (void)out_size; (void)ws_size;
    const float* x   = (const float*)d_in[0];
    const float* Wq  = (const float*)d_in[1];
    const float* Wk  = (const float*)d_in[2];
    const float* Wog = (const float*)d_in[3];
    const float* Wig = (const float*)d_in[4];
    const float* gw  = (const float*)d_in[5];
    float* out = (float*)d_out;

    float* ws = (float*)d_ws;
    const size_t MK = (size_t)B_ * L_ * KD_;   // 524288
    const size_t MH = (size_t)B_ * L_ * H_;    // 8388608
    float* q  = ws;
    float* ks = q + MK;
    float* g  = ks + MK;
    float* G  = g + MK;
    float* o  = G + MK;
    float* rr = o + MH;
    unsigned short* Abuf = (unsigned short*)(rr + 4096);   // [4096][4096] bf16
    unsigned short* Bbuf = Abuf + (size_t)4096 * K2_;      // [2048][4096] bf16
    unsigned short* qt_b = Bbuf + (size_t)2048 * K2_;      // [4096][128] bf16
    unsigned short* kA_b = qt_b + MK;
    unsigned short* kB_b = kA_b + MK;
    // ws use: ~42 MB fp32 + 48 MB bf16 GEMM bufs + 3 MB scaled q/k = ~93 MB

    qk_proj_kernel<<<dim3(64, 4), 256, 0, stream>>>(x, Wq, Wk, q, ks, g);
    gate_scan_kernel<<<dim3(KD_, B_), 64, 0, stream>>>(g, G);
    qk_scale_kernel<<<256, 256, 0, stream>>>(q, ks, G, qt_b, kA_b, kB_b);
    cast_x_half<<<4096, 256, 0, stream>>>(x, Abuf);
    cast_concat_B<<<8192, 256, 0, stream>>>(Wog, Wig, Bbuf);
    gla_attn_mfma<<<dim3(32, B_, 16), 256, 0, stream>>>(qt_b, kA_b, kB_b, Abuf, o);
    row_rms_kernel<<<B_ * L_, 256, 0, stream>>>(o, rr);
    out_gemm_mfma<<<dim3(32, 16), 256, 0, stream>>>(Abuf, Bbuf, o, gw, rr, out);
}

// Round 4
// 294.728 us; speedup vs baseline: 9.5832x; 1.4568x over previous
//
#include <hip/hip_runtime.h>
#include <math.h>

// Problem constants (B=2, L=2048, H=2048, K=H/NH=128)
#define B_ 2
#define L_ 2048
#define H_ 2048
#define KD_ 128
#define SCALE_ 0.08838834764831845f  // 128^-0.5
#define EPS_ 1e-5f
#define K2_ 4096                     // concat-K for the dual output GEMM

typedef __bf16 bf16x8 __attribute__((ext_vector_type(8)));
typedef float f32x4 __attribute__((ext_vector_type(4)));

static __device__ __forceinline__ float sigmoidf_(float z) {
    return 1.0f / (1.0f + __expf(-z));
}

static __device__ __forceinline__ unsigned short f2bf(float f) {
    unsigned int u = __float_as_uint(f);
    unsigned int r = (u + 0x7fffu + ((u >> 16) & 1u)) >> 16;
    return (unsigned short)r;
}

// async global->LDS, 16B per lane; lds base must be wave-uniform
#define ASYNC_COPY16(gsrc, ldst)                                             \
    __builtin_amdgcn_global_load_lds(                                        \
        (const __attribute__((address_space(1))) unsigned int*)(gsrc),       \
        (__attribute__((address_space(3))) unsigned int*)(ldst), 16, 0, 0)

// ---------------------------------------------------------------------------
// Kernel 0a: cast x -> bf16 into the x-half of Abuf (cols 2048..4095).
// (also serves as the A-operand for the qk projection GEMM)
// ---------------------------------------------------------------------------
__global__ __launch_bounds__(256) void cast_x_half(
    const float* __restrict__ x, unsigned short* __restrict__ Abuf)
{
    size_t i = (size_t)blockIdx.x * 256 + threadIdx.x;   // group of 8 floats
    size_t m = i >> 8;
    size_t c8 = (i & 255) * 8;
    float4 v0 = *(const float4*)(x + m * H_ + c8);
    float4 v1 = *(const float4*)(x + m * H_ + c8 + 4);
    ushort4 a, b;
    a.x = f2bf(v0.x); a.y = f2bf(v0.y); a.z = f2bf(v0.z); a.w = f2bf(v0.w);
    b.x = f2bf(v1.x); b.y = f2bf(v1.y); b.z = f2bf(v1.z); b.w = f2bf(v1.w);
    unsigned short* dst = Abuf + m * K2_ + H_ + c8;
    *(ushort4*)dst = a;
    *(ushort4*)(dst + 4) = b;
}

// Kernel 0b: cast [Wq | Wk] -> bf16 [256][2048]
__global__ __launch_bounds__(256) void cast_Wqk(
    const float* __restrict__ Wq, const float* __restrict__ Wk,
    unsigned short* __restrict__ Wqk)
{
    size_t i = (size_t)blockIdx.x * 256 + threadIdx.x;   // group of 8 floats
    const size_t half = (size_t)KD_ * H_ / 8;            // 32768 groups per W
    const float* src = (i < half) ? Wq : Wk;
    size_t j = (i < half) ? i : i - half;
    float4 v0 = *(const float4*)(src + j * 8);
    float4 v1 = *(const float4*)(src + j * 8 + 4);
    ushort4 a, b;
    a.x = f2bf(v0.x); a.y = f2bf(v0.y); a.z = f2bf(v0.z); a.w = f2bf(v0.w);
    b.x = f2bf(v1.x); b.y = f2bf(v1.y); b.z = f2bf(v1.z); b.w = f2bf(v1.w);
    unsigned short* dst = Wqk + i * 8;
    *(ushort4*)dst = a;
    *(ushort4*)(dst + 4) = b;
}

// ---------------------------------------------------------------------------
// Kernel 1: qk projection GEMM via MFMA, split-K.
// A = x bf16 (Abuf x-half, row stride K2_), B = Wqk [256][2048] bf16.
// M=4096, N=256, K=2048 split into 4 slices of 512.
// Grid (32, 2, 4) = 256 blocks. Partials fp32 [4][4096][256].
// ---------------------------------------------------------------------------
__global__ __launch_bounds__(256) void qk_proj_mfma(
    const unsigned short* __restrict__ Abuf,
    const unsigned short* __restrict__ Wqk,
    float* __restrict__ partial)
{
    __shared__ alignas(16) unsigned short As[128 * 64];
    __shared__ alignas(16) unsigned short Bs[128 * 64];
    const int tid  = threadIdx.x;
    const int wave = tid >> 6;
    const int lane = tid & 63;
    const int m0 = blockIdx.x * 128;
    const int n0 = blockIdx.y * 128;
    const int kz = blockIdx.z * 512;
    const int wm = (wave >> 1) * 64;
    const int wn = (wave & 1) * 64;

    f32x4 acc[4][4] = {};

    const int se  = lane * 8;
    const int ldsbase = (wave * 4) * 512;
    const int frow = lane & 15;
    const int fk   = (lane >> 4) * 8;

    for (int k0 = kz; k0 < kz + 512; k0 += 64) {
        #pragma unroll
        for (int it = 0; it < 4; ++it) {
            int e = ldsbase + it * 512 + se;
            int r = e >> 6, cc = e & 63;
            const unsigned short* ga =
                Abuf + (size_t)(m0 + r) * K2_ + H_ + k0 + cc;
            ASYNC_COPY16(ga, &As[e]);
            const unsigned short* gb = Wqk + (size_t)(n0 + r) * H_ + k0 + cc;
            ASYNC_COPY16(gb, &Bs[e]);
        }
        __syncthreads();
        #pragma unroll
        for (int ksub = 0; ksub < 2; ++ksub) {
            bf16x8 af[4], bf[4];
            #pragma unroll
            for (int i = 0; i < 4; ++i)
                af[i] = *(const bf16x8*)(As + (wm + i * 16 + frow) * 64 + ksub * 32 + fk);
            #pragma unroll
            for (int j = 0; j < 4; ++j)
                bf[j] = *(const bf16x8*)(Bs + (wn + j * 16 + frow) * 64 + ksub * 32 + fk);
            #pragma unroll
            for (int i = 0; i < 4; ++i)
                #pragma unroll
                for (int j = 0; j < 4; ++j)
                    acc[i][j] = __builtin_amdgcn_mfma_f32_16x16x32_bf16(
                        af[i], bf[j], acc[i][j], 0, 0, 0);
        }
        __syncthreads();
    }

    float* pz = partial + (size_t)blockIdx.z * 4096 * 256;
    #pragma unroll
    for (int i = 0; i < 4; ++i) {
        #pragma unroll
        for (int reg = 0; reg < 4; ++reg) {
            int m = m0 + wm + i * 16 + (lane >> 4) * 4 + reg;
            #pragma unroll
            for (int j = 0; j < 4; ++j) {
                int n = n0 + wn + j * 16 + (lane & 15);
                pz[(size_t)m * 256 + n] = acc[i][j][reg];
            }
        }
    }
}

// ---------------------------------------------------------------------------
// Kernel 1b: reduce the 4 K-slices + epilogue.
//   n<128: q = silu(v)*SCALE ; n>=128: ks = sigmoid(v), g = -log1p(exp(ks))
// ---------------------------------------------------------------------------
__global__ __launch_bounds__(256) void qk_reduce_kernel(
    const float* __restrict__ partial, float* __restrict__ q,
    float* __restrict__ ks, float* __restrict__ g)
{
    const size_t idx = (size_t)blockIdx.x * 256 + threadIdx.x;  // group of 4
    const size_t m = idx >> 6;
    const int col = (int)(idx & 63) * 4;
    const size_t off = m * 256 + col;
    const size_t stride = (size_t)4096 * 256;
    float4 s = *(const float4*)(partial + off);
    #pragma unroll
    for (int z = 1; z < 4; ++z) {
        float4 p = *(const float4*)(partial + z * stride + off);
        s.x += p.x; s.y += p.y; s.z += p.z; s.w += p.w;
    }
    float v[4] = {s.x, s.y, s.z, s.w};
    if (col < 128) {
        float r[4];
        #pragma unroll
        for (int j = 0; j < 4; ++j) r[j] = v[j] * sigmoidf_(v[j]) * SCALE_;
        *(float4*)(q + m * KD_ + col) = *(float4*)r;
    } else {
        float sk[4], gg[4];
        #pragma unroll
        for (int j = 0; j < 4; ++j) {
            sk[j] = sigmoidf_(v[j]);
            gg[j] = -log1pf(__expf(sk[j]));
        }
        *(float4*)(ks + m * KD_ + col - 128) = *(float4*)sk;
        *(float4*)(g + m * KD_ + col - 128)  = *(float4*)gg;
    }
}

// ---------------------------------------------------------------------------
// Kernel 2: inclusive prefix sum of g along L per (batch, key-dim).
// ---------------------------------------------------------------------------
__global__ __launch_bounds__(64) void gate_scan_kernel(
    const float* __restrict__ g, float* __restrict__ G)
{
    const int kd = blockIdx.x;
    const int b  = blockIdx.y;
    const int lane = threadIdx.x;
    const float* gp = g + (size_t)b * L_ * KD_ + kd;
    float* Gp = G + (size_t)b * L_ * KD_ + kd;
    float vals[32];
    float s = 0.f;
    const int t0 = lane * 32;
    #pragma unroll
    for (int j = 0; j < 32; ++j) { s += gp[(size_t)(t0 + j) * KD_]; vals[j] = s; }
    float incl = s;
    #pragma unroll
    for (int d = 1; d < 64; d <<= 1) {
        float n = __shfl_up(incl, d, 64);
        if (lane >= d) incl += n;
    }
    float excl = incl - s;
    #pragma unroll
    for (int j = 0; j < 32; ++j) Gp[(size_t)(t0 + j) * KD_] = excl + vals[j];
}

// ---------------------------------------------------------------------------
// Kernel 3a: chunk-referenced scaled q/k in bf16.
//   For row t (chunk c = t>>6, R1 = G[c*64-1], R2 = G[c*64+63]):
//     qt = q * exp(G - R1) ; kA = ks * exp(R1 - G) ; kB = ks * exp(R2 - G)
// ---------------------------------------------------------------------------
__global__ __launch_bounds__(256) void qk_scale_kernel(
    const float* __restrict__ q, const float* __restrict__ ks,
    const float* __restrict__ G, unsigned short* __restrict__ qt_b,
    unsigned short* __restrict__ kA_b, unsigned short* __restrict__ kB_b)
{
    const int tid = threadIdx.x;
    const int r = blockIdx.x * 16 + (tid >> 4);      // 0..4095
    const int d0 = (tid & 15) * 8;
    const int t = r & (L_ - 1);
    const bool has_prev = (t >= 64);
    const bool last = ((t >> 6) == (L_ / 64 - 1));
    const size_t base = (size_t)r * KD_ + d0;
    const size_t r1base = (size_t)((r & ~63) - 1) * KD_ + d0;
    const size_t r2base = (size_t)(r | 63) * KD_ + d0;

    float qv[8], kv[8], Gv[8], R1[8], R2[8];
    *(float4*)(qv)     = *(const float4*)(q + base);
    *(float4*)(qv + 4) = *(const float4*)(q + base + 4);
    *(float4*)(kv)     = *(const float4*)(ks + base);
    *(float4*)(kv + 4) = *(const float4*)(ks + base + 4);
    *(float4*)(Gv)     = *(const float4*)(G + base);
    *(float4*)(Gv + 4) = *(const float4*)(G + base + 4);
    if (has_prev) {
        *(float4*)(R1)     = *(const float4*)(G + r1base);
        *(float4*)(R1 + 4) = *(const float4*)(G + r1base + 4);
    } else {
        #pragma unroll
        for (int j = 0; j < 8; ++j) R1[j] = 0.f;
    }
    if (!last) {
        *(float4*)(R2)     = *(const float4*)(G + r2base);
        *(float4*)(R2 + 4) = *(const float4*)(G + r2base + 4);
    }
    unsigned short oq[8], oa[8], ob[8];
    #pragma unroll
    for (int j = 0; j < 8; ++j) {
        oq[j] = f2bf(qv[j] * __expf(Gv[j] - R1[j]));
        oa[j] = f2bf(kv[j] * __expf(R1[j] - Gv[j]));
        ob[j] = last ? (unsigned short)0 : f2bf(kv[j] * __expf(R2[j] - Gv[j]));
    }
    *(ushort4*)(qt_b + base)     = *(ushort4*)(oq);
    *(ushort4*)(qt_b + base + 4) = *(ushort4*)(oq + 4);
    *(ushort4*)(kA_b + base)     = *(ushort4*)(oa);
    *(ushort4*)(kA_b + base + 4) = *(ushort4*)(oa + 4);
    *(ushort4*)(kB_b + base)     = *(ushort4*)(ob);
    *(ushort4*)(kB_b + base + 4) = *(ushort4*)(ob + 4);
}

// ---------------------------------------------------------------------------
// Kernel 3c: banded GLA attention, all-MFMA.
// ---------------------------------------------------------------------------
#define SV_ 130   // Vt row stride (elems)
#define SP_ 136   // Psh row stride (elems)

__global__ __launch_bounds__(256) void gla_attn_mfma(
    const unsigned short* __restrict__ qt_b,
    const unsigned short* __restrict__ kA_b,
    const unsigned short* __restrict__ kB_b,
    unsigned short* Abuf,          // reads x-half (cols 2048+), writes o-half
    float* __restrict__ o)
{
    const int c  = blockIdx.x;   // chunk 0..31
    const int b  = blockIdx.y;
    const int vt = blockIdx.z;   // 0..15
    const int tid = threadIdx.x;
    const int w = tid >> 6, l = tid & 63;
    const int lr = l & 15, lq = l >> 4;
    const int q0 = c * 64, kpos0 = q0 - 64, v0c = vt * 128;
    const size_t rowbase = (size_t)b * L_;

    __shared__ alignas(16) unsigned short Vt[128 * SV_];
    __shared__ alignas(16) unsigned short Psh[64 * SP_];

    // ---- stage V transposed: Vt[vcol][key] ----
    {
        const int a = tid & 15;       // col group (8 cols)
        const int kr0 = tid >> 4;
        for (int kr = kr0; kr < 128; kr += 16) {
            int kp = kpos0 + kr;
            ushort4 u0 = {0, 0, 0, 0}, u1 = {0, 0, 0, 0};
            if (kp >= 0) {
                const unsigned short* src =
                    Abuf + (rowbase + kp) * K2_ + H_ + v0c + a * 8;
                u0 = *(const ushort4*)src;
                u1 = *(const ushort4*)(src + 4);
            }
            unsigned short vals[8] = {u0.x, u0.y, u0.z, u0.w,
                                      u1.x, u1.y, u1.z, u1.w};
            #pragma unroll
            for (int j = 0; j < 8; ++j)
                Vt[(a * 8 + j) * SV_ + kr] = vals[j];
        }
    }

    // ---- phase 1: P = qt . k~^T ----
    bf16x8 aq[4];
    {
        const unsigned short* qrow = qt_b + (rowbase + q0 + 16 * w + lr) * KD_;
        #pragma unroll
        for (int kt = 0; kt < 4; ++kt)
            aq[kt] = *(const bf16x8*)(qrow + kt * 32 + lq * 8);
    }
    #pragma unroll
    for (int jt = 0; jt < 8; ++jt) {
        f32x4 p = {};
        const int si = jt * 16 + lr;          // window key index 0..127
        const bool prev = (jt < 4);
        const bool dead = (c == 0 && prev);
        if (!dead) {
            int kp = prev ? (kpos0 + si) : (q0 + si - 64);
            const unsigned short* kb = (prev ? kB_b : kA_b) + (rowbase + kp) * KD_;
            #pragma unroll
            for (int kt = 0; kt < 4; ++kt) {
                bf16x8 bk = *(const bf16x8*)(kb + kt * 32 + lq * 8);
                p = __builtin_amdgcn_mfma_f32_16x16x32_bf16(aq[kt], bk, p, 0, 0, 0);
            }
        }
        #pragma unroll
        for (int reg = 0; reg < 4; ++reg) {
            int ti = 16 * w + lq * 4 + reg;   // q row 0..63
            bool keep = !dead && (si <= ti + 64);
            Psh[ti * SP_ + si] = keep ? f2bf(p[reg]) : (unsigned short)0;
        }
    }
    __syncthreads();

    // ---- phase 2: O = P @ V ----
    bf16x8 ap[4];
    #pragma unroll
    for (int kt = 0; kt < 4; ++kt)
        ap[kt] = *(const bf16x8*)(Psh + (16 * w + lr) * SP_ + kt * 32 + lq * 8);
    #pragma unroll
    for (int jt = 0; jt < 8; ++jt) {
        f32x4 oa = {};
        const int n = jt * 16 + lr;
        #pragma unroll
        for (int kt = 0; kt < 4; ++kt) {
            const unsigned int* vp =
                (const unsigned int*)(Vt + n * SV_ + kt * 32 + lq * 8);
            union { unsigned int u[4]; bf16x8 v; } bb;
            bb.u[0] = vp[0]; bb.u[1] = vp[1]; bb.u[2] = vp[2]; bb.u[3] = vp[3];
            oa = __builtin_amdgcn_mfma_f32_16x16x32_bf16(ap[kt], bb.v, oa, 0, 0, 0);
        }
        #pragma unroll
        for (int reg = 0; reg < 4; ++reg) {
            int qrow = 16 * w + lq * 4 + reg;
            size_t orow = rowbase + q0 + qrow;
            float val = oa[reg];
            o[orow * H_ + v0c + n] = val;
            Abuf[orow * K2_ + v0c + n] = f2bf(val);
        }
    }
}

// ---------------------------------------------------------------------------
// Kernel 4a: per-row rsqrt(mean(o^2)+eps), float4 loads.
// ---------------------------------------------------------------------------
__global__ __launch_bounds__(256) void row_rms_kernel(
    const float* __restrict__ o, float* __restrict__ rrms)
{
    const int m = blockIdx.x;
    const int tid = threadIdx.x;
    const float* row = o + (size_t)m * H_;
    float s = 0.f;
    #pragma unroll
    for (int it = 0; it < 2; ++it) {
        float4 v = *(const float4*)(row + (it * 256 + tid) * 4);
        s += v.x * v.x + v.y * v.y + v.z * v.z + v.w * v.w;
    }
    #pragma unroll
    for (int d = 32; d > 0; d >>= 1) s += __shfl_down(s, d, 64);
    __shared__ float red[4];
    if ((tid & 63) == 0) red[tid >> 6] = s;
    __syncthreads();
    if (tid == 0)
        rrms[m] = rsqrtf((red[0] + red[1] + red[2] + red[3]) * (1.0f / H_) + EPS_);
}

// Kernel 4b-prep: cast/concat B = [Wog | Wig] -> bf16 [2048][4096]
__global__ __launch_bounds__(256) void cast_concat_B(
    const float* __restrict__ Wog, const float* __restrict__ Wig,
    unsigned short* __restrict__ Bbuf)
{
    size_t i = (size_t)blockIdx.x * 256 + threadIdx.x;
    const size_t half = (size_t)2048 * 512;
    const float* src = (i < half) ? Wog : Wig;
    size_t j = (i < half) ? i : i - half;
    size_t n = j >> 9;
    size_t c4 = (j & 511) * 4;
    float4 v = *(const float4*)(src + n * H_ + c4);
    ushort4 bb;
    bb.x = f2bf(v.x); bb.y = f2bf(v.y); bb.z = f2bf(v.z); bb.w = f2bf(v.w);
    size_t off = (i < half) ? 0 : H_;
    *(ushort4*)(Bbuf + n * K2_ + off + c4) = bb;
}

// ---------------------------------------------------------------------------
// Kernel 4b: go = A @ B^T via bf16 MFMA (m97 structure). Fused epilogue:
// out = (o*rrms*gw) * go * sigmoid(go).  M=4096, N=2048, K=4096.
// ---------------------------------------------------------------------------
__global__ __launch_bounds__(256) void out_gemm_mfma(
    const unsigned short* __restrict__ Abuf,
    const unsigned short* __restrict__ Bbuf,
    const float* __restrict__ o, const float* __restrict__ gw,
    const float* __restrict__ rrms, float* __restrict__ out)
{
    __shared__ alignas(16) unsigned short As[128 * 64];
    __shared__ alignas(16) unsigned short Bs[128 * 64];
    const int tid  = threadIdx.x;
    const int wave = tid >> 6;
    const int lane = tid & 63;
    const int m0 = blockIdx.x * 128;
    const int n0 = blockIdx.y * 128;
    const int wm = (wave >> 1) * 64;
    const int wn = (wave & 1) * 64;

    f32x4 acc[4][4] = {};

    const int se  = lane * 8;
    const int ldsbase = (wave * 4) * 512;
    const int frow = lane & 15;
    const int fk   = (lane >> 4) * 8;

    for (int k0 = 0; k0 < K2_; k0 += 64) {
        #pragma unroll
        for (int it = 0; it < 4; ++it) {
            int e = ldsbase + it * 512 + se;
            int r = e >> 6, cc = e & 63;
            const unsigned short* ga = Abuf + (size_t)(m0 + r) * K2_ + k0 + cc;
            ASYNC_COPY16(ga, &As[e]);
            const unsigned short* gb = Bbuf + (size_t)(n0 + r) * K2_ + k0 + cc;
            ASYNC_COPY16(gb, &Bs[e]);
        }
        __syncthreads();
        #pragma unroll
        for (int ksub = 0; ksub < 2; ++ksub) {
            bf16x8 af[4], bf[4];
            #pragma unroll
            for (int i = 0; i < 4; ++i)
                af[i] = *(const bf16x8*)(As + (wm + i * 16 + frow) * 64 + ksub * 32 + fk);
            #pragma unroll
            for (int j = 0; j < 4; ++j)
                bf[j] = *(const bf16x8*)(Bs + (wn + j * 16 + frow) * 64 + ksub * 32 + fk);
            #pragma unroll
            for (int i = 0; i < 4; ++i)
                #pragma unroll
                for (int j = 0; j < 4; ++j)
                    acc[i][j] = __builtin_amdgcn_mfma_f32_16x16x32_bf16(
                        af[i], bf[j], acc[i][j], 0, 0, 0);
        }
        __syncthreads();
    }

    #pragma unroll
    for (int i = 0; i < 4; ++i) {
        #pragma unroll
        for (int reg = 0; reg < 4; ++reg) {
            int m = m0 + wm + i * 16 + (lane >> 4) * 4 + reg;
            float rv = rrms[m];
            #pragma unroll
            for (int j = 0; j < 4; ++j) {
                int n = n0 + wn + j * 16 + (lane & 15);
                float go = acc[i][j][reg];
                float ov = o[(size_t)m * H_ + n];
                out[(size_t)m * H_ + n] = ov * rv * gw[n] * go * sigmoidf_(go);
            }
        }
    }
}

// ---------------------------------------------------------------------------
extern "C" void kernel_launch(void* const* d_in, const int* in_sizes, int n_in,
                              void* d_out, int out_size, void* d_ws, size_t ws_size,
                              hipStream_t stream) {
    (void)in_sizes; (void)n_in; (void)out_size; (void)ws_size;
    const float* x   = (const float*)d_in[0];
    const float* Wq  = (const float*)d_in[1];
    const float* Wk  = (const float*)d_in[2];
    const float* Wog = (const float*)d_in[3];
    const float* Wig = (const float*)d_in[4];
    const float* gw  = (const float*)d_in[5];
    float* out = (float*)d_out;

    float* ws = (float*)d_ws;
    const size_t MK = (size_t)B_ * L_ * KD_;   // 524288
    const size_t MH = (size_t)B_ * L_ * H_;    // 8388608
    float* q  = ws;
    float* ks = q + MK;
    float* g  = ks + MK;
    float* G  = g + MK;
    float* o  = G + MK;
    float* rr = o + MH;
    unsigned short* Abuf = (unsigned short*)(rr + 4096);   // [4096][4096] bf16
    unsigned short* Bbuf = Abuf + (size_t)4096 * K2_;      // [2048][4096] bf16
    unsigned short* qt_b = Bbuf + (size_t)2048 * K2_;      // [4096][128] bf16
    unsigned short* kA_b = qt_b + MK;
    unsigned short* kB_b = kA_b + MK;
    unsigned short* Wqk  = kB_b + MK;                      // [256][2048] bf16
    float* partial = (float*)(Wqk + (size_t)256 * H_);     // [4][4096][256] fp32
    // ws use: ~42 MB fp32 + 48 MB bf16 + 3 MB qk + 1 MB W + 16 MB partial ~ 110 MB

    cast_x_half<<<4096, 256, 0, stream>>>(x, Abuf);
    cast_Wqk<<<256, 256, 0, stream>>>(Wq, Wk, Wqk);
    qk_proj_mfma<<<dim3(32, 2, 4), 256, 0, stream>>>(Abuf, Wqk, partial);
    qk_reduce_kernel<<<1024, 256, 0, stream>>>(partial, q, ks, g);
    gate_scan_kernel<<<dim3(KD_, B_), 64, 0, stream>>>(g, G);
    qk_scale_kernel<<<256, 256, 0, stream>>>(q, ks, G, qt_b, kA_b, kB_b);
    cast_concat_B<<<8192, 256, 0, stream>>>(Wog, Wig, Bbuf);
    gla_attn_mfma<<<dim3(32, B_, 16), 256, 0, stream>>>(qt_b, kA_b, kB_b, Abuf, o);
    row_rms_kernel<<<B_ * L_, 256, 0, stream>>>(o, rr);
    out_gemm_mfma<<<dim3(32, 16), 256, 0, stream>>>(Abuf, Bbuf, o, gw, rr, out);
}